// Round 5
// baseline (218.004 us; speedup 1.0000x reference)
//
#include <hip/hip_runtime.h>
#include <cstdint>

#define DIM 768
#define NH 12
#define HD 64
#define SEQ 1024
#define NBH 96

// ws layout (u16 elements)
#define QOFF  ((size_t)0)
#define KOFF  ((size_t)6291456)
#define VOFF  ((size_t)12582912)
#define AOFF  ((size_t)18874368)   // attn output bf16 [8192][768]
#define XOFF  ((size_t)25165824)   // x bf16
#define WQOFF ((size_t)31457280)   // w_qkv^T bf16 [2304][768]
#define WPOFF ((size_t)33226752)   // w_proj^T bf16 [768][768]

#define QSCALE 0.18033688f  /* 0.125 * log2(e) */

// s_waitcnt immediates: vmcnt[3:0]@[3:0], expcnt@[6:4], lgkmcnt@[11:8], vmcnt[5:4]@[15:14]
#define WAIT_VM8   __builtin_amdgcn_s_waitcnt(0x0F78)  /* vmcnt(8) only  */
#define WAIT_VM0   __builtin_amdgcn_s_waitcnt(0x0F70)  /* vmcnt(0) only  */
#define WAIT_LGKM0 __builtin_amdgcn_s_waitcnt(0xC07F)  /* lgkmcnt(0) only */
#define BAR        __builtin_amdgcn_s_barrier()
#define CFENCE     __asm__ __volatile__("" ::: "memory")

typedef __attribute__((ext_vector_type(8))) __bf16 bf16x8;
typedef __attribute__((ext_vector_type(2))) __bf16 bf16x2;
typedef __attribute__((ext_vector_type(4))) float f32x4;
typedef unsigned short u16;

__device__ __forceinline__ u16 f2bf(float f) {
    union { float f; unsigned u; } x; x.f = f;
    unsigned r = x.u + 0x7fffu + ((x.u >> 16) & 1u);
    return (u16)(r >> 16);
}

__device__ __forceinline__ unsigned pkbf(float a, float b) {
#if __has_builtin(__builtin_amdgcn_cvt_pk_bf16_f32)
    bf16x2 v = __builtin_amdgcn_cvt_pk_bf16_f32(a, b);
    union { bf16x2 v; unsigned u; } c; c.v = v; return c.u;
#else
    return (unsigned)f2bf(a) | ((unsigned)f2bf(b) << 16);
#endif
}

__device__ __forceinline__ void async_cp16(const void* g, void* l) {
    __builtin_amdgcn_global_load_lds((const __attribute__((address_space(1))) void*)g,
                                     (__attribute__((address_space(3))) void*)l, 16, 0, 0);
}

// ---- fused prep: x fp32->bf16, plus both weight transposes (fp32 [K][N] -> bf16 [N][K])
__global__ __launch_bounds__(256) void prep(const float* __restrict__ x,
                                            const float* __restrict__ wq,
                                            const float* __restrict__ wp,
                                            u16* __restrict__ ws) {
    const int bid = blockIdx.x;
    const int tid = threadIdx.x;
    if (bid < 6144) {
        int i = bid * 256 + tid;
        float4 v = *(const float4*)&x[(size_t)i * 4];
        ushort4 o; o.x = f2bf(v.x); o.y = f2bf(v.y); o.z = f2bf(v.z); o.w = f2bf(v.w);
        *(ushort4*)&ws[XOFF + (size_t)i * 4] = o;
        return;
    }
    __shared__ float T[64][65];
    const float* w; u16* wt; int N, bx, by;
    if (bid < 6576) { int b = bid - 6144; w = wq; wt = ws + WQOFF; N = 2304; bx = b % 36; by = b / 36; }
    else            { int b = bid - 6576; w = wp; wt = ws + WPOFF; N = 768;  bx = b % 12; by = b / 12; }
    const int K = 768;
    const int k0 = by * 64, n0 = bx * 64;
    const int r = tid >> 4, c4 = (tid & 15) * 4;
#pragma unroll
    for (int i = 0; i < 4; ++i) {
        float4 v = *(const float4*)&w[(size_t)(k0 + r + 16 * i) * N + n0 + c4];
        T[r + 16 * i][c4 + 0] = v.x; T[r + 16 * i][c4 + 1] = v.y;
        T[r + 16 * i][c4 + 2] = v.z; T[r + 16 * i][c4 + 3] = v.w;
    }
    __syncthreads();
#pragma unroll
    for (int i = 0; i < 4; ++i) {
        int rr = r + 16 * i;
        ushort4 o;
        o.x = f2bf(T[c4 + 0][rr]); o.y = f2bf(T[c4 + 1][rr]);
        o.z = f2bf(T[c4 + 2][rr]); o.w = f2bf(T[c4 + 3][rr]);
        *(ushort4*)&wt[(size_t)(n0 + rr) * K + k0 + c4] = o;
    }
}

// ---- pipelined GEMM (unchanged from R4): 128x128 tile, BK=64, dbuf LDS, vmcnt(8) pipeline
template <int EPI>
__global__ __launch_bounds__(256) void gemm_bt(const u16* __restrict__ A,
                                               const u16* __restrict__ Bt,
                                               const float* __restrict__ bias,
                                               float* __restrict__ outf,
                                               u16* __restrict__ outq) {
    __shared__ __align__(16) u16 As[2][128 * 64];
    __shared__ __align__(16) u16 Bs[2][128 * 64];
    const int tid = threadIdx.x;
    const int lane = tid & 63;
    const int w = tid >> 6;
    const int wm = w >> 1, wn = w & 1;
    const int m0 = blockIdx.y * 128, n0 = blockIdx.x * 128;

    const int lgrp = lane >> 3;
    const int gg = (lane & 7) ^ lgrp;
    const u16* ga = A  + (size_t)(m0 + w * 32 + lgrp) * 768 + gg * 8;
    const u16* gb = Bt + (size_t)(n0 + w * 32 + lgrp) * 768 + gg * 8;

    const int l15 = lane & 15, qg = lane >> 4, q4 = qg * 4;

    int aoff[4][2], boff[4][2];
#pragma unroll
    for (int r = 0; r < 4; ++r) {
        int row = 64 * wm + 16 * r + l15;
#pragma unroll
        for (int kc = 0; kc < 2; ++kc)
            aoff[r][kc] = row * 64 + (((4 * kc + qg) ^ (row & 7)) << 3);
    }
#pragma unroll
    for (int c = 0; c < 4; ++c) {
        int row = 64 * wn + 16 * c + l15;
#pragma unroll
        for (int kc = 0; kc < 2; ++kc)
            boff[c][kc] = row * 64 + (((4 * kc + qg) ^ (row & 7)) << 3);
    }

#define ISSUE(buf, kk)                                                          \
    {                                                                           \
        _Pragma("unroll")                                                       \
        for (int i = 0; i < 4; ++i) {                                           \
            async_cp16(ga + (size_t)i * 8 * 768 + (kk), &As[buf][w * 2048 + i * 512]); \
            async_cp16(gb + (size_t)i * 8 * 768 + (kk), &Bs[buf][w * 2048 + i * 512]); \
        }                                                                       \
    }

    ISSUE(0, 0)
    ISSUE(1, 64)

    f32x4 acc[4][4] = {};

#pragma unroll
    for (int k = 0; k < 12; ++k) {
        const int cur = k & 1;
        if (k < 11) { WAIT_VM8; } else { WAIT_VM0; }
        BAR;
        CFENCE;
        bf16x8 af[4][2], bfr[4][2];
#pragma unroll
        for (int r = 0; r < 4; ++r)
#pragma unroll
            for (int kc = 0; kc < 2; ++kc) af[r][kc] = *(const bf16x8*)&As[cur][aoff[r][kc]];
#pragma unroll
        for (int c = 0; c < 4; ++c)
#pragma unroll
            for (int kc = 0; kc < 2; ++kc) bfr[c][kc] = *(const bf16x8*)&Bs[cur][boff[c][kc]];
        WAIT_LGKM0;
        CFENCE;
        BAR;
        if (k + 2 < 12) ISSUE(cur, (k + 2) * 64)
#pragma unroll
        for (int kc = 0; kc < 2; ++kc)
#pragma unroll
            for (int r = 0; r < 4; ++r)
#pragma unroll
                for (int c = 0; c < 4; ++c)
                    acc[r][c] = __builtin_amdgcn_mfma_f32_16x16x32_bf16(af[r][kc], bfr[c][kc], acc[r][c], 0, 0, 0);
    }
#undef ISSUE

#pragma unroll
    for (int r = 0; r < 4; ++r) {
#pragma unroll
        for (int c = 0; c < 4; ++c) {
            const int cg = n0 + 64 * wn + 16 * c + l15;
            const float bv = bias[cg];
            const int mb = m0 + 64 * wm + 16 * r + q4;
            if constexpr (EPI == 0) {
#pragma unroll
                for (int g = 0; g < 4; ++g)
                    outf[(size_t)(mb + g) * DIM + cg] = acc[r][c][g] + bv;
            } else {
                const int which = (cg >= 1536) ? 2 : (cg >= 768 ? 1 : 0);
                const int rem = cg - which * 768;
                const int h = rem >> 6, d = rem & 63;
                const int b = mb >> 10, q = mb & 1023;
                if (which == 0) {
#pragma unroll
                    for (int g = 0; g < 4; ++g)
                        outq[QOFF + ((size_t)(b * NH + h) * SEQ + q + g) * HD + d] =
                            f2bf((acc[r][c][g] + bv) * QSCALE);
                } else if (which == 1) {
#pragma unroll
                    for (int g = 0; g < 4; ++g)
                        outq[KOFF + ((size_t)(b * NH + h) * SEQ + q + g) * HD + d] =
                            f2bf(acc[r][c][g] + bv);
                } else {
                    ushort4 pk;
                    pk.x = f2bf(acc[r][c][0] + bv); pk.y = f2bf(acc[r][c][1] + bv);
                    pk.z = f2bf(acc[r][c][2] + bv); pk.w = f2bf(acc[r][c][3] + bv);
                    *(ushort4*)&outq[VOFF + ((size_t)(b * NH + h) * HD + d) * SEQ + q] = pk;
                }
            }
        }
    }
}

// ---- Flash attention v3: no-max exp2 softmax (Q prescaled), S transposed (A=K, B=Q),
// V B-frags straight from global (no LDS), XOR-swizzled unpadded Ks/Ps,
// double-buffered async K staging with 2-barrier pipeline.
__global__ __launch_bounds__(256) void flash_attn(const u16* __restrict__ ws, u16* __restrict__ attn_out) {
    __shared__ __align__(16) u16 Ks[2][64 * 64];
    __shared__ __align__(16) u16 Ps[128 * 64];

    const int tid = threadIdx.x;
    const int lane = tid & 63;
    const int wv = tid >> 6;
    const int qt = blockIdx.x;   // 0..7
    const int bh = blockIdx.y;   // 0..95
    const u16* qp = ws + QOFF + (size_t)bh * SEQ * HD;
    const u16* kp = ws + KOFF + (size_t)bh * SEQ * HD;
    const u16* vp = ws + VOFF + (size_t)bh * HD * SEQ;

    const int l15 = lane & 15, qg = lane >> 4, q8 = qg * 8, q4 = qg * 4;
    const int l7 = l15 & 7;

    // Q B-frags (B[k][n]: lane n=q=...+l15, 8 consecutive k) — wave owns q rows 32wv..+31
    bf16x8 bq[2][2];
#pragma unroll
    for (int r = 0; r < 2; ++r)
#pragma unroll
        for (int kc = 0; kc < 2; ++kc)
            bq[r][kc] = *(const bf16x8*)&qp[(size_t)(qt * 128 + 32 * wv + 16 * r + l15) * HD + 32 * kc + q8];

    // K async staging: global col-group swizzled, LDS linear (wave-uniform base + lane*16B)
    const int lgrp = lane >> 3;
    const int gg = (lane & 7) ^ lgrp;
    auto kissue = [&](int buf, int ktv) {
#pragma unroll
        for (int i = 0; i < 2; ++i)
            async_cp16(kp + (size_t)(ktv * 64 + wv * 16 + i * 8 + lgrp) * 64 + gg * 8,
                       &Ks[buf][(wv * 16 + i * 8) * 64]);
    };
    kissue(0, 0);

    // LDS read offsets (swizzled, stride 64 u16)
    int akoff[4][2], apoff[2][2], pwoff[2][4];
#pragma unroll
    for (int c = 0; c < 4; ++c)
#pragma unroll
        for (int kc = 0; kc < 2; ++kc)
            akoff[c][kc] = (16 * c + l15) * 64 + (((4 * kc + qg) ^ l7) << 3);
#pragma unroll
    for (int r = 0; r < 2; ++r) {
#pragma unroll
        for (int kc = 0; kc < 2; ++kc)
            apoff[r][kc] = (32 * wv + 16 * r + l15) * 64 + (((4 * kc + qg) ^ l7) << 3);
#pragma unroll
        for (int c = 0; c < 4; ++c)
            pwoff[r][c] = (32 * wv + 16 * r + l15) * 64 + (((2 * c + (qg >> 1)) ^ l7) << 3) + (qg & 1) * 4;
    }

    f32x4 oacc[2][4] = {};
    float lsum[2] = {0.f, 0.f};

    for (int kt = 0; kt < 16; ++kt) {
        const int cur = kt & 1;
        WAIT_VM0;   // K[cur] landed (issued one iteration ago; hidden by PV)
        BAR;
        CFENCE;

        // V B-frags from global (L1-filtered; consumed in PV below)
        bf16x8 bv[4][2];
#pragma unroll
        for (int cd = 0; cd < 4; ++cd)
#pragma unroll
            for (int kc = 0; kc < 2; ++kc)
                bv[cd][kc] = *(const bf16x8*)&vp[(size_t)(16 * cd + l15) * SEQ + kt * 64 + 32 * kc + q8];

        // St = K Q^T  (C-layout: col=q=l15, row=key=qg*4+g within 16-tile)
        f32x4 sacc[4][2] = {};
#pragma unroll
        for (int c = 0; c < 4; ++c) {
#pragma unroll
            for (int kc = 0; kc < 2; ++kc) {
                bf16x8 ak = *(const bf16x8*)&Ks[cur][akoff[c][kc]];
#pragma unroll
                for (int r = 0; r < 2; ++r)
                    sacc[c][r] = __builtin_amdgcn_mfma_f32_16x16x32_bf16(ak, bq[r][kc], sacc[c][r], 0, 0, 0);
            }
        }

        // exp2 (no max), packed bf16 converts, b64 P stores into A-layout
#pragma unroll
        for (int r = 0; r < 2; ++r) {
#pragma unroll
            for (int c = 0; c < 4; ++c) {
                float p0 = __builtin_amdgcn_exp2f(sacc[c][r][0]);
                float p1 = __builtin_amdgcn_exp2f(sacc[c][r][1]);
                float p2 = __builtin_amdgcn_exp2f(sacc[c][r][2]);
                float p3 = __builtin_amdgcn_exp2f(sacc[c][r][3]);
                lsum[r] += (p0 + p1) + (p2 + p3);
                uint2 pk2; pk2.x = pkbf(p0, p1); pk2.y = pkbf(p2, p3);
                *(uint2*)&Ps[pwoff[r][c]] = pk2;
            }
        }

        CFENCE;
        WAIT_LGKM0;   // my P writes visible
        BAR;          // all waves' P writes visible; all ak reads of Ks[!cur] long done
        CFENCE;
        if (kt < 15) kissue(cur ^ 1, kt + 1);   // K[kt+1] in flight across PV

        // O += P V
#pragma unroll
        for (int r = 0; r < 2; ++r) {
#pragma unroll
            for (int kc = 0; kc < 2; ++kc) {
                bf16x8 ap = *(const bf16x8*)&Ps[apoff[r][kc]];
#pragma unroll
                for (int cd = 0; cd < 4; ++cd)
                    oacc[r][cd] = __builtin_amdgcn_mfma_f32_16x16x32_bf16(ap, bv[cd][kc], oacc[r][cd], 0, 0, 0);
            }
        }
    }

    // final l reduction across the 4 qg-groups (wave covers all keys for its q rows)
#pragma unroll
    for (int r = 0; r < 2; ++r) {
        lsum[r] += __shfl_xor(lsum[r], 16);
        lsum[r] += __shfl_xor(lsum[r], 32);
    }
    float linv[2][4];
#pragma unroll
    for (int r = 0; r < 2; ++r)
#pragma unroll
        for (int g = 0; g < 4; ++g)
            linv[r][g] = 1.f / __shfl(lsum[r], q4 + g);

    const int b = bh / NH, h = bh % NH;
#pragma unroll
    for (int r = 0; r < 2; ++r) {
#pragma unroll
        for (int g = 0; g < 4; ++g) {
            int qrow = qt * 128 + 32 * wv + 16 * r + q4 + g;
            size_t grow = (size_t)(b * SEQ + qrow) * DIM + h * HD;
#pragma unroll
            for (int cd = 0; cd < 4; ++cd)
                attn_out[grow + 16 * cd + l15] = f2bf(oacc[r][cd][g] * linv[r][g]);
        }
    }
}

extern "C" void kernel_launch(void* const* d_in, const int* in_sizes, int n_in,
                              void* d_out, int out_size, void* d_ws, size_t ws_size,
                              hipStream_t stream) {
    const float* x      = (const float*)d_in[0];
    const float* w_qkv  = (const float*)d_in[1];
    const float* b_qkv  = (const float*)d_in[2];
    const float* w_proj = (const float*)d_in[3];
    const float* b_proj = (const float*)d_in[4];
    float* out = (float*)d_out;
    u16* ws = (u16*)d_ws;

    prep<<<6720, 256, 0, stream>>>(x, w_qkv, w_proj, ws);
    gemm_bt<1><<<dim3(18, 64), 256, 0, stream>>>(ws + XOFF, ws + WQOFF, b_qkv, nullptr, ws);
    flash_attn<<<dim3(8, 96), 256, 0, stream>>>(ws, ws + AOFF);
    gemm_bt<0><<<dim3(6, 64), 256, 0, stream>>>(ws + AOFF, ws + WPOFF, b_proj, out, nullptr);
}

// Round 6
// 214.581 us; speedup vs baseline: 1.0160x; 1.0160x over previous
//
#include <hip/hip_runtime.h>
#include <cstdint>

#define DIM 768
#define NH 12
#define HD 64
#define SEQ 1024
#define NBH 96

// ws layout (u16 elements)
#define QOFF  ((size_t)0)
#define KOFF  ((size_t)6291456)
#define VOFF  ((size_t)12582912)
#define AOFF  ((size_t)18874368)   // attn output bf16 [8192][768]
#define XOFF  ((size_t)25165824)   // x bf16
#define WQOFF ((size_t)31457280)   // w_qkv^T bf16 [2304][768]
#define WPOFF ((size_t)33226752)   // w_proj^T bf16 [768][768]

#define QSCALE 0.18033688f  /* 0.125 * log2(e) */

// s_waitcnt immediates: vmcnt[3:0]@[3:0], expcnt@[6:4], lgkmcnt@[11:8], vmcnt[5:4]@[15:14]
#define WAIT_VM8   __builtin_amdgcn_s_waitcnt(0x0F78)  /* vmcnt(8) only  */
#define WAIT_VM0   __builtin_amdgcn_s_waitcnt(0x0F70)  /* vmcnt(0) only  */
#define WAIT_LGKM0 __builtin_amdgcn_s_waitcnt(0xC07F)  /* lgkmcnt(0) only */
#define BAR        __builtin_amdgcn_s_barrier()
#define CFENCE     __asm__ __volatile__("" ::: "memory")

typedef __attribute__((ext_vector_type(8))) __bf16 bf16x8;
typedef __attribute__((ext_vector_type(2))) __bf16 bf16x2;
typedef __attribute__((ext_vector_type(4))) float f32x4;
typedef __attribute__((ext_vector_type(4))) short s16x4;
typedef unsigned short u16;

__device__ __forceinline__ u16 f2bf(float f) {
    union { float f; unsigned u; } x; x.f = f;
    unsigned r = x.u + 0x7fffu + ((x.u >> 16) & 1u);
    return (u16)(r >> 16);
}

__device__ __forceinline__ unsigned pkbf(float a, float b) {
#if __has_builtin(__builtin_amdgcn_cvt_pk_bf16_f32)
    bf16x2 v = __builtin_amdgcn_cvt_pk_bf16_f32(a, b);
    union { bf16x2 v; unsigned u; } c; c.v = v; return c.u;
#else
    return (unsigned)f2bf(a) | ((unsigned)f2bf(b) << 16);
#endif
}

__device__ __forceinline__ void async_cp16(const void* g, void* l) {
    __builtin_amdgcn_global_load_lds((const __attribute__((address_space(1))) void*)g,
                                     (__attribute__((address_space(3))) void*)l, 16, 0, 0);
}

// ---- fused prep: x fp32->bf16, plus both weight transposes (fp32 [K][N] -> bf16 [N][K])
__global__ __launch_bounds__(256) void prep(const float* __restrict__ x,
                                            const float* __restrict__ wq,
                                            const float* __restrict__ wp,
                                            u16* __restrict__ ws) {
    const int bid = blockIdx.x;
    const int tid = threadIdx.x;
    if (bid < 6144) {
        int i = bid * 256 + tid;
        float4 v = *(const float4*)&x[(size_t)i * 4];
        ushort4 o; o.x = f2bf(v.x); o.y = f2bf(v.y); o.z = f2bf(v.z); o.w = f2bf(v.w);
        *(ushort4*)&ws[XOFF + (size_t)i * 4] = o;
        return;
    }
    __shared__ float T[64][65];
    const float* w; u16* wt; int N, bx, by;
    if (bid < 6576) { int b = bid - 6144; w = wq; wt = ws + WQOFF; N = 2304; bx = b % 36; by = b / 36; }
    else            { int b = bid - 6576; w = wp; wt = ws + WPOFF; N = 768;  bx = b % 12; by = b / 12; }
    const int K = 768;
    const int k0 = by * 64, n0 = bx * 64;
    const int r = tid >> 4, c4 = (tid & 15) * 4;
#pragma unroll
    for (int i = 0; i < 4; ++i) {
        float4 v = *(const float4*)&w[(size_t)(k0 + r + 16 * i) * N + n0 + c4];
        T[r + 16 * i][c4 + 0] = v.x; T[r + 16 * i][c4 + 1] = v.y;
        T[r + 16 * i][c4 + 2] = v.z; T[r + 16 * i][c4 + 3] = v.w;
    }
    __syncthreads();
#pragma unroll
    for (int i = 0; i < 4; ++i) {
        int rr = r + 16 * i;
        ushort4 o;
        o.x = f2bf(T[c4 + 0][rr]); o.y = f2bf(T[c4 + 1][rr]);
        o.z = f2bf(T[c4 + 2][rr]); o.w = f2bf(T[c4 + 3][rr]);
        *(ushort4*)&wt[(size_t)(n0 + rr) * K + k0 + c4] = o;
    }
}

// ---- pipelined GEMM (unchanged from R4): 128x128 tile, BK=64, dbuf LDS, vmcnt(8) pipeline
template <int EPI>
__global__ __launch_bounds__(256) void gemm_bt(const u16* __restrict__ A,
                                               const u16* __restrict__ Bt,
                                               const float* __restrict__ bias,
                                               float* __restrict__ outf,
                                               u16* __restrict__ outq) {
    __shared__ __align__(16) u16 As[2][128 * 64];
    __shared__ __align__(16) u16 Bs[2][128 * 64];
    const int tid = threadIdx.x;
    const int lane = tid & 63;
    const int w = tid >> 6;
    const int wm = w >> 1, wn = w & 1;
    const int m0 = blockIdx.y * 128, n0 = blockIdx.x * 128;

    const int lgrp = lane >> 3;
    const int gg = (lane & 7) ^ lgrp;
    const u16* ga = A  + (size_t)(m0 + w * 32 + lgrp) * 768 + gg * 8;
    const u16* gb = Bt + (size_t)(n0 + w * 32 + lgrp) * 768 + gg * 8;

    const int l15 = lane & 15, qg = lane >> 4, q4 = qg * 4;

    int aoff[4][2], boff[4][2];
#pragma unroll
    for (int r = 0; r < 4; ++r) {
        int row = 64 * wm + 16 * r + l15;
#pragma unroll
        for (int kc = 0; kc < 2; ++kc)
            aoff[r][kc] = row * 64 + (((4 * kc + qg) ^ (row & 7)) << 3);
    }
#pragma unroll
    for (int c = 0; c < 4; ++c) {
        int row = 64 * wn + 16 * c + l15;
#pragma unroll
        for (int kc = 0; kc < 2; ++kc)
            boff[c][kc] = row * 64 + (((4 * kc + qg) ^ (row & 7)) << 3);
    }

#define ISSUE(buf, kk)                                                          \
    {                                                                           \
        _Pragma("unroll")                                                       \
        for (int i = 0; i < 4; ++i) {                                           \
            async_cp16(ga + (size_t)i * 8 * 768 + (kk), &As[buf][w * 2048 + i * 512]); \
            async_cp16(gb + (size_t)i * 8 * 768 + (kk), &Bs[buf][w * 2048 + i * 512]); \
        }                                                                       \
    }

    ISSUE(0, 0)
    ISSUE(1, 64)

    f32x4 acc[4][4] = {};

#pragma unroll
    for (int k = 0; k < 12; ++k) {
        const int cur = k & 1;
        if (k < 11) { WAIT_VM8; } else { WAIT_VM0; }
        BAR;
        CFENCE;
        bf16x8 af[4][2], bfr[4][2];
#pragma unroll
        for (int r = 0; r < 4; ++r)
#pragma unroll
            for (int kc = 0; kc < 2; ++kc) af[r][kc] = *(const bf16x8*)&As[cur][aoff[r][kc]];
#pragma unroll
        for (int c = 0; c < 4; ++c)
#pragma unroll
            for (int kc = 0; kc < 2; ++kc) bfr[c][kc] = *(const bf16x8*)&Bs[cur][boff[c][kc]];
        WAIT_LGKM0;
        CFENCE;
        BAR;
        if (k + 2 < 12) ISSUE(cur, (k + 2) * 64)
#pragma unroll
        for (int kc = 0; kc < 2; ++kc)
#pragma unroll
            for (int r = 0; r < 4; ++r)
#pragma unroll
                for (int c = 0; c < 4; ++c)
                    acc[r][c] = __builtin_amdgcn_mfma_f32_16x16x32_bf16(af[r][kc], bfr[c][kc], acc[r][c], 0, 0, 0);
    }
#undef ISSUE

#pragma unroll
    for (int r = 0; r < 4; ++r) {
#pragma unroll
        for (int c = 0; c < 4; ++c) {
            const int cg = n0 + 64 * wn + 16 * c + l15;
            const float bv = bias[cg];
            const int mb = m0 + 64 * wm + 16 * r + q4;
            if constexpr (EPI == 0) {
#pragma unroll
                for (int g = 0; g < 4; ++g)
                    outf[(size_t)(mb + g) * DIM + cg] = acc[r][c][g] + bv;
            } else {
                const int which = (cg >= 1536) ? 2 : (cg >= 768 ? 1 : 0);
                const int rem = cg - which * 768;
                const int h = rem >> 6, d = rem & 63;
                const int b = mb >> 10, q = mb & 1023;
                if (which == 0) {
#pragma unroll
                    for (int g = 0; g < 4; ++g)
                        outq[QOFF + ((size_t)(b * NH + h) * SEQ + q + g) * HD + d] =
                            f2bf((acc[r][c][g] + bv) * QSCALE);
                } else if (which == 1) {
#pragma unroll
                    for (int g = 0; g < 4; ++g)
                        outq[KOFF + ((size_t)(b * NH + h) * SEQ + q + g) * HD + d] =
                            f2bf(acc[r][c][g] + bv);
                } else {
                    ushort4 pk;
                    pk.x = f2bf(acc[r][c][0] + bv); pk.y = f2bf(acc[r][c][1] + bv);
                    pk.z = f2bf(acc[r][c][2] + bv); pk.w = f2bf(acc[r][c][3] + bv);
                    *(ushort4*)&outq[VOFF + ((size_t)(b * NH + h) * HD + d) * SEQ + q] = pk;
                }
            }
        }
    }
}

// ---- Flash attention v4: P never touches LDS.
// St = K·Q^T via 16x16x32 (A=K from LDS, B=Q regs) -> C-layout col=q=l15, row=key=qg*4+reg.
// That layout IS the B-operand layout of v_mfma_f32_16x16x16_bf16 (B[k=qg*4+j][n=l15], k=key).
// So exp2+pack in regs feeds PV directly: O^T[d][q] += A(V^T[d][key]) x B(P[key][q]).
// K and V both async-staged to LDS (dbuf, XOR-swizzled); ONE barrier per kt-tile.
__global__ __launch_bounds__(256) void flash_attn(const u16* __restrict__ ws, u16* __restrict__ attn_out) {
    __shared__ __align__(16) u16 Ks[2][64 * 64];
    __shared__ __align__(16) u16 Vs[2][64 * 64];

    const int tid = threadIdx.x;
    const int lane = tid & 63;
    const int wv = tid >> 6;
    const int qt = blockIdx.x;   // 0..7
    const int bh = blockIdx.y;   // 0..95
    const u16* qp = ws + QOFF + (size_t)bh * SEQ * HD;
    const u16* kp = ws + KOFF + (size_t)bh * SEQ * HD;
    const u16* vp = ws + VOFF + (size_t)bh * HD * SEQ;

    const int l15 = lane & 15, qg = lane >> 4, q8 = qg * 8;
    const int l7 = l15 & 7;

    // Q B-frags for QK (B[k=dim][n=q]): wave owns q rows 32wv..+31
    bf16x8 bq[2][2];
#pragma unroll
    for (int r = 0; r < 2; ++r)
#pragma unroll
        for (int kc = 0; kc < 2; ++kc)
            bq[r][kc] = *(const bf16x8*)&qp[(size_t)(qt * 128 + 32 * wv + 16 * r + l15) * HD + 32 * kc + q8];

    // async staging (wave-split rows, XOR-8 16B-group swizzle; LDS linear)
    const int lgrp = lane >> 3;
    const int gg = (lane & 7) ^ lgrp;
    auto stage = [&](int buf, int ktv) {
#pragma unroll
        for (int i = 0; i < 2; ++i) {
            async_cp16(kp + (size_t)(ktv * 64 + wv * 16 + i * 8 + lgrp) * 64 + gg * 8,
                       &Ks[buf][(wv * 16 + i * 8) * 64]);
            async_cp16(vp + (size_t)(wv * 16 + i * 8 + lgrp) * SEQ + ktv * 64 + gg * 8,
                       &Vs[buf][(wv * 16 + i * 8) * 64]);
        }
    };
    stage(0, 0);

    // LDS read offsets (swizzled, stride 64 u16)
    int akoff[4][2], avoff[4][4];
#pragma unroll
    for (int c = 0; c < 4; ++c) {
#pragma unroll
        for (int kc = 0; kc < 2; ++kc)
            akoff[c][kc] = (16 * c + l15) * 64 + (((4 * kc + qg) ^ l7) << 3);
#pragma unroll
        for (int cd = 0; cd < 4; ++cd)   // V^T A-frag: row=d=16cd+l15, keys 16c+qg*4.. (8B)
            avoff[c][cd] = (16 * cd + l15) * 64 + (((2 * c + (qg >> 1)) ^ l7) << 3) + (qg & 1) * 4;
    }

    f32x4 oacc[2][4] = {};   // O^T: [r][cd], D col=q=l15, row=d=16cd+qg*4+reg
    float lsum[2] = {0.f, 0.f};

    for (int kt = 0; kt < 16; ++kt) {
        const int cur = kt & 1;
        WAIT_VM0;    // own staging for buf[cur] done (issued a full iteration ago)
        BAR;         // everyone's staging done; everyone finished reading buf[cur^1]
        CFENCE;
        if (kt < 15) stage(cur ^ 1, kt + 1);   // in flight across entire QK+softmax+PV

        // St = K Q^T (16x16x32): sacc[c][r] covers keys 16c.., q 32wv+16r..
        f32x4 sacc[4][2] = {};
#pragma unroll
        for (int c = 0; c < 4; ++c) {
#pragma unroll
            for (int kc = 0; kc < 2; ++kc) {
                bf16x8 ak = *(const bf16x8*)&Ks[cur][akoff[c][kc]];
#pragma unroll
                for (int r = 0; r < 2; ++r)
                    sacc[c][r] = __builtin_amdgcn_mfma_f32_16x16x32_bf16(ak, bq[r][kc], sacc[c][r], 0, 0, 0);
            }
        }

        // exp2 (no max; Q prescaled) + in-register pack to PV B-frags
        s16x4 pf[4][2];
#pragma unroll
        for (int c = 0; c < 4; ++c) {
#pragma unroll
            for (int r = 0; r < 2; ++r) {
                float p0 = __builtin_amdgcn_exp2f(sacc[c][r][0]);
                float p1 = __builtin_amdgcn_exp2f(sacc[c][r][1]);
                float p2 = __builtin_amdgcn_exp2f(sacc[c][r][2]);
                float p3 = __builtin_amdgcn_exp2f(sacc[c][r][3]);
                lsum[r] += (p0 + p1) + (p2 + p3);
                union { uint2 u; s16x4 v; } pk;
                pk.u.x = pkbf(p0, p1); pk.u.y = pkbf(p2, p3);
                pf[c][r] = pk.v;
            }
        }

        // O^T += V^T · P  (16x16x16: A = V^T frag from LDS, B = pf in regs)
#pragma unroll
        for (int c = 0; c < 4; ++c) {
            s16x4 av[4];
#pragma unroll
            for (int cd = 0; cd < 4; ++cd)
                av[cd] = *(const s16x4*)&Vs[cur][avoff[c][cd]];
#pragma unroll
            for (int r = 0; r < 2; ++r)
#pragma unroll
                for (int cd = 0; cd < 4; ++cd)
                    oacc[r][cd] = __builtin_amdgcn_mfma_f32_16x16x16bf16_1k(av[cd], pf[c][r], oacc[r][cd], 0, 0, 0);
        }
    }

    // l: sum across the 4 qg groups; every lane then holds the sum for its q=l15
#pragma unroll
    for (int r = 0; r < 2; ++r) {
        lsum[r] += __shfl_xor(lsum[r], 16);
        lsum[r] += __shfl_xor(lsum[r], 32);
    }

    // epilogue: O^T D-layout (col=q=l15, row=d=16cd+qg*4+reg) -> attn[b*SEQ+q][h*64+d], ushort4 along d
    const int b = bh / NH, h = bh % NH;
#pragma unroll
    for (int r = 0; r < 2; ++r) {
        const float inv = 1.f / lsum[r];
        const int qrow = qt * 128 + 32 * wv + 16 * r + l15;
        u16* orow = attn_out + (size_t)(b * SEQ + qrow) * DIM + h * HD + qg * 4;
#pragma unroll
        for (int cd = 0; cd < 4; ++cd) {
            ushort4 o;
            o.x = f2bf(oacc[r][cd][0] * inv); o.y = f2bf(oacc[r][cd][1] * inv);
            o.z = f2bf(oacc[r][cd][2] * inv); o.w = f2bf(oacc[r][cd][3] * inv);
            *(ushort4*)&orow[16 * cd] = o;
        }
    }
}

extern "C" void kernel_launch(void* const* d_in, const int* in_sizes, int n_in,
                              void* d_out, int out_size, void* d_ws, size_t ws_size,
                              hipStream_t stream) {
    const float* x      = (const float*)d_in[0];
    const float* w_qkv  = (const float*)d_in[1];
    const float* b_qkv  = (const float*)d_in[2];
    const float* w_proj = (const float*)d_in[3];
    const float* b_proj = (const float*)d_in[4];
    float* out = (float*)d_out;
    u16* ws = (u16*)d_ws;

    prep<<<6720, 256, 0, stream>>>(x, w_qkv, w_proj, ws);
    gemm_bt<1><<<dim3(18, 64), 256, 0, stream>>>(ws + XOFF, ws + WQOFF, b_qkv, nullptr, ws);
    flash_attn<<<dim3(8, 96), 256, 0, stream>>>(ws, ws + AOFF);
    gemm_bt<0><<<dim3(6, 64), 256, 0, stream>>>(ws + AOFF, ws + WPOFF, b_proj, out, nullptr);
}

// Round 7
// 207.677 us; speedup vs baseline: 1.0497x; 1.0332x over previous
//
#include <hip/hip_runtime.h>
#include <cstdint>

#define DIM 768
#define NH 12
#define HD 64
#define SEQ 1024
#define NBH 96

// ws layout (u16 elements)
#define QOFF  ((size_t)0)
#define KOFF  ((size_t)6291456)
#define VOFF  ((size_t)12582912)
#define AOFF  ((size_t)18874368)   // attn output bf16 [8192][768]
#define XOFF  ((size_t)25165824)   // x bf16
#define WQOFF ((size_t)31457280)   // w_qkv^T bf16 [2304][768]
#define WPOFF ((size_t)33226752)   // w_proj^T bf16 [768][768]

#define QSCALE 0.18033688f  /* 0.125 * log2(e) */

// s_waitcnt immediates: vmcnt[3:0]@[3:0], expcnt@[6:4], lgkmcnt@[11:8], vmcnt[5:4]@[15:14]
#define WAIT_VM0   __builtin_amdgcn_s_waitcnt(0x0F70)  /* vmcnt(0) only  */
#define BAR        __builtin_amdgcn_s_barrier()
#define CFENCE     __asm__ __volatile__("" ::: "memory")

typedef __attribute__((ext_vector_type(8))) __bf16 bf16x8;
typedef __attribute__((ext_vector_type(2))) __bf16 bf16x2;
typedef __attribute__((ext_vector_type(4))) float f32x4;
typedef __attribute__((ext_vector_type(4))) short s16x4;
typedef unsigned short u16;

__device__ __forceinline__ u16 f2bf(float f) {
    union { float f; unsigned u; } x; x.f = f;
    unsigned r = x.u + 0x7fffu + ((x.u >> 16) & 1u);
    return (u16)(r >> 16);
}

__device__ __forceinline__ unsigned pkbf(float a, float b) {
#if __has_builtin(__builtin_amdgcn_cvt_pk_bf16_f32)
    bf16x2 v = __builtin_amdgcn_cvt_pk_bf16_f32(a, b);
    union { bf16x2 v; unsigned u; } c; c.v = v; return c.u;
#else
    return (unsigned)f2bf(a) | ((unsigned)f2bf(b) << 16);
#endif
}

__device__ __forceinline__ void async_cp16(const void* g, void* l) {
    __builtin_amdgcn_global_load_lds((const __attribute__((address_space(1))) void*)g,
                                     (__attribute__((address_space(3))) void*)l, 16, 0, 0);
}

// ---- fused prep: x fp32->bf16 (2 float4/thread), plus both weight transposes
__global__ __launch_bounds__(256) void prep(const float* __restrict__ x,
                                            const float* __restrict__ wq,
                                            const float* __restrict__ wp,
                                            u16* __restrict__ ws) {
    const int bid = blockIdx.x;
    const int tid = threadIdx.x;
    if (bid < 3072) {
        size_t i = (size_t)bid * 512 + tid;
#pragma unroll
        for (int j = 0; j < 2; ++j, i += 256) {
            float4 v = *(const float4*)&x[i * 4];
            ushort4 o;
            o.x = f2bf(v.x); o.y = f2bf(v.y); o.z = f2bf(v.z); o.w = f2bf(v.w);
            *(ushort4*)&ws[XOFF + i * 4] = o;
        }
        return;
    }
    __shared__ float T[64][65];
    const float* w; u16* wt; int N, bx, by;
    if (bid < 3504) { int b = bid - 3072; w = wq; wt = ws + WQOFF; N = 2304; bx = b % 36; by = b / 36; }
    else            { int b = bid - 3504; w = wp; wt = ws + WPOFF; N = 768;  bx = b % 12; by = b / 12; }
    const int K = 768;
    const int k0 = by * 64, n0 = bx * 64;
    const int r = tid >> 4, c4 = (tid & 15) * 4;
#pragma unroll
    for (int i = 0; i < 4; ++i) {
        float4 v = *(const float4*)&w[(size_t)(k0 + r + 16 * i) * N + n0 + c4];
        T[r + 16 * i][c4 + 0] = v.x; T[r + 16 * i][c4 + 1] = v.y;
        T[r + 16 * i][c4 + 2] = v.z; T[r + 16 * i][c4 + 3] = v.w;
    }
    __syncthreads();
#pragma unroll
    for (int i = 0; i < 4; ++i) {
        int rr = r + 16 * i;
        ushort4 o;
        o.x = f2bf(T[c4 + 0][rr]); o.y = f2bf(T[c4 + 1][rr]);
        o.z = f2bf(T[c4 + 2][rr]); o.w = f2bf(T[c4 + 3][rr]);
        *(ushort4*)&wt[(size_t)(n0 + rr) * K + k0 + c4] = o;
    }
}

// ---- GEMM, R3 structure (single 32KB buffer, syncthreads — measured 59us @qkv):
// A[M][768] bf16, Bt[N][768] bf16; 128x128 tile, BK=64, global_load_lds w=16, XOR-8 swizzle.
// EPI=0: out fp32 [M][768] + bias.  EPI=1: qkv scatter (Q prescaled, V transposed).
template <int EPI>
__global__ __launch_bounds__(256) void gemm_bt(const u16* __restrict__ A,
                                               const u16* __restrict__ Bt,
                                               const float* __restrict__ bias,
                                               float* __restrict__ outf,
                                               u16* __restrict__ outq) {
    __shared__ __align__(16) u16 As[128 * 64];
    __shared__ __align__(16) u16 Bs[128 * 64];
    const int tid = threadIdx.x;
    const int lane = tid & 63;
    const int w = tid >> 6;
    const int wm = w >> 1, wn = w & 1;
    const int m0 = blockIdx.y * 128, n0 = blockIdx.x * 128;

    const int lgrp = lane >> 3;             // row-within-8
    const int gg = (lane & 7) ^ lgrp;       // swizzled global k-group for staging
    const u16* ga = A  + (size_t)(m0 + w * 32 + lgrp) * 768 + gg * 8;
    const u16* gb = Bt + (size_t)(n0 + w * 32 + lgrp) * 768 + gg * 8;
    u16* lba = As + w * 4 * 512;
    u16* lbb = Bs + w * 4 * 512;

    const int l15 = lane & 15, qg = lane >> 4, q4 = qg * 4;

    int aoff[4][2], boff[4][2];
#pragma unroll
    for (int r = 0; r < 4; ++r) {
        int row = 64 * wm + 16 * r + l15;
#pragma unroll
        for (int kc = 0; kc < 2; ++kc)
            aoff[r][kc] = row * 64 + (((4 * kc + qg) ^ (row & 7)) << 3);
    }
#pragma unroll
    for (int c = 0; c < 4; ++c) {
        int row = 64 * wn + 16 * c + l15;
#pragma unroll
        for (int kc = 0; kc < 2; ++kc)
            boff[c][kc] = row * 64 + (((4 * kc + qg) ^ (row & 7)) << 3);
    }

    f32x4 acc[4][4] = {};

    for (int k0 = 0; k0 < 768; k0 += 64) {
#pragma unroll
        for (int i = 0; i < 4; ++i) {
            async_cp16(ga + (size_t)i * 8 * 768 + k0, lba + i * 512);
            async_cp16(gb + (size_t)i * 8 * 768 + k0, lbb + i * 512);
        }
        __syncthreads();
        bf16x8 af[4][2], bfr[4][2];
#pragma unroll
        for (int r = 0; r < 4; ++r)
#pragma unroll
            for (int kc = 0; kc < 2; ++kc) af[r][kc] = *(const bf16x8*)&As[aoff[r][kc]];
#pragma unroll
        for (int c = 0; c < 4; ++c)
#pragma unroll
            for (int kc = 0; kc < 2; ++kc) bfr[c][kc] = *(const bf16x8*)&Bs[boff[c][kc]];
#pragma unroll
        for (int kc = 0; kc < 2; ++kc)
#pragma unroll
            for (int r = 0; r < 4; ++r)
#pragma unroll
                for (int c = 0; c < 4; ++c)
                    acc[r][c] = __builtin_amdgcn_mfma_f32_16x16x32_bf16(af[r][kc], bfr[c][kc], acc[r][c], 0, 0, 0);
        __syncthreads();
    }

#pragma unroll
    for (int r = 0; r < 4; ++r) {
#pragma unroll
        for (int c = 0; c < 4; ++c) {
            const int cg = n0 + 64 * wn + 16 * c + l15;
            const float bv = bias[cg];
            const int mb = m0 + 64 * wm + 16 * r + q4;
            if constexpr (EPI == 0) {
#pragma unroll
                for (int g = 0; g < 4; ++g)
                    outf[(size_t)(mb + g) * DIM + cg] = acc[r][c][g] + bv;
            } else {
                const int which = (cg >= 1536) ? 2 : (cg >= 768 ? 1 : 0);  // uniform over l15
                const int rem = cg - which * 768;
                const int h = rem >> 6, d = rem & 63;
                const int b = mb >> 10, q = mb & 1023;
                if (which == 0) {
#pragma unroll
                    for (int g = 0; g < 4; ++g)
                        outq[QOFF + ((size_t)(b * NH + h) * SEQ + q + g) * HD + d] =
                            f2bf((acc[r][c][g] + bv) * QSCALE);
                } else if (which == 1) {
#pragma unroll
                    for (int g = 0; g < 4; ++g)
                        outq[KOFF + ((size_t)(b * NH + h) * SEQ + q + g) * HD + d] =
                            f2bf(acc[r][c][g] + bv);
                } else {
                    ushort4 pk;
                    pk.x = f2bf(acc[r][c][0] + bv); pk.y = f2bf(acc[r][c][1] + bv);
                    pk.z = f2bf(acc[r][c][2] + bv); pk.w = f2bf(acc[r][c][3] + bv);
                    *(ushort4*)&outq[VOFF + ((size_t)(b * NH + h) * HD + d) * SEQ + q] = pk;
                }
            }
        }
    }
}

// ---- Flash attention v4 (unchanged from R6): P never touches LDS.
// St = K·Q^T via 16x16x32 (A=K LDS, B=Q regs) -> C-layout col=q=l15, row=key=qg*4+reg,
// which IS the 16x16x16 B-operand layout -> PV directly from regs.
// K,V async dbuf staging; ONE barrier per kt-tile.
__global__ __launch_bounds__(256) void flash_attn(const u16* __restrict__ ws, u16* __restrict__ attn_out) {
    __shared__ __align__(16) u16 Ks[2][64 * 64];
    __shared__ __align__(16) u16 Vs[2][64 * 64];

    const int tid = threadIdx.x;
    const int lane = tid & 63;
    const int wv = tid >> 6;
    const int qt = blockIdx.x;   // 0..7
    const int bh = blockIdx.y;   // 0..95
    const u16* qp = ws + QOFF + (size_t)bh * SEQ * HD;
    const u16* kp = ws + KOFF + (size_t)bh * SEQ * HD;
    const u16* vp = ws + VOFF + (size_t)bh * HD * SEQ;

    const int l15 = lane & 15, qg = lane >> 4, q8 = qg * 8;
    const int l7 = l15 & 7;

    bf16x8 bq[2][2];
#pragma unroll
    for (int r = 0; r < 2; ++r)
#pragma unroll
        for (int kc = 0; kc < 2; ++kc)
            bq[r][kc] = *(const bf16x8*)&qp[(size_t)(qt * 128 + 32 * wv + 16 * r + l15) * HD + 32 * kc + q8];

    const int lgrp = lane >> 3;
    const int gg = (lane & 7) ^ lgrp;
    auto stage = [&](int buf, int ktv) {
#pragma unroll
        for (int i = 0; i < 2; ++i) {
            async_cp16(kp + (size_t)(ktv * 64 + wv * 16 + i * 8 + lgrp) * 64 + gg * 8,
                       &Ks[buf][(wv * 16 + i * 8) * 64]);
            async_cp16(vp + (size_t)(wv * 16 + i * 8 + lgrp) * SEQ + ktv * 64 + gg * 8,
                       &Vs[buf][(wv * 16 + i * 8) * 64]);
        }
    };
    stage(0, 0);

    int akoff[4][2], avoff[4][4];
#pragma unroll
    for (int c = 0; c < 4; ++c) {
#pragma unroll
        for (int kc = 0; kc < 2; ++kc)
            akoff[c][kc] = (16 * c + l15) * 64 + (((4 * kc + qg) ^ l7) << 3);
#pragma unroll
        for (int cd = 0; cd < 4; ++cd)
            avoff[c][cd] = (16 * cd + l15) * 64 + (((2 * c + (qg >> 1)) ^ l7) << 3) + (qg & 1) * 4;
    }

    f32x4 oacc[2][4] = {};   // O^T: D col=q=l15, row=d=16cd+qg*4+reg
    float lsum[2] = {0.f, 0.f};

    for (int kt = 0; kt < 16; ++kt) {
        const int cur = kt & 1;
        WAIT_VM0;
        BAR;
        CFENCE;
        if (kt < 15) stage(cur ^ 1, kt + 1);

        f32x4 sacc[4][2] = {};
#pragma unroll
        for (int c = 0; c < 4; ++c) {
#pragma unroll
            for (int kc = 0; kc < 2; ++kc) {
                bf16x8 ak = *(const bf16x8*)&Ks[cur][akoff[c][kc]];
#pragma unroll
                for (int r = 0; r < 2; ++r)
                    sacc[c][r] = __builtin_amdgcn_mfma_f32_16x16x32_bf16(ak, bq[r][kc], sacc[c][r], 0, 0, 0);
            }
        }

        s16x4 pf[4][2];
#pragma unroll
        for (int c = 0; c < 4; ++c) {
#pragma unroll
            for (int r = 0; r < 2; ++r) {
                float p0 = __builtin_amdgcn_exp2f(sacc[c][r][0]);
                float p1 = __builtin_amdgcn_exp2f(sacc[c][r][1]);
                float p2 = __builtin_amdgcn_exp2f(sacc[c][r][2]);
                float p3 = __builtin_amdgcn_exp2f(sacc[c][r][3]);
                lsum[r] += (p0 + p1) + (p2 + p3);
                union { uint2 u; s16x4 v; } pk;
                pk.u.x = pkbf(p0, p1); pk.u.y = pkbf(p2, p3);
                pf[c][r] = pk.v;
            }
        }

#pragma unroll
        for (int c = 0; c < 4; ++c) {
            s16x4 av[4];
#pragma unroll
            for (int cd = 0; cd < 4; ++cd)
                av[cd] = *(const s16x4*)&Vs[cur][avoff[c][cd]];
#pragma unroll
            for (int r = 0; r < 2; ++r)
#pragma unroll
                for (int cd = 0; cd < 4; ++cd)
                    oacc[r][cd] = __builtin_amdgcn_mfma_f32_16x16x16bf16_1k(av[cd], pf[c][r], oacc[r][cd], 0, 0, 0);
        }
    }

#pragma unroll
    for (int r = 0; r < 2; ++r) {
        lsum[r] += __shfl_xor(lsum[r], 16);
        lsum[r] += __shfl_xor(lsum[r], 32);
    }

    const int b = bh / NH, h = bh % NH;
#pragma unroll
    for (int r = 0; r < 2; ++r) {
        const float inv = 1.f / lsum[r];
        const int qrow = qt * 128 + 32 * wv + 16 * r + l15;
        u16* orow = attn_out + (size_t)(b * SEQ + qrow) * DIM + h * HD + qg * 4;
#pragma unroll
        for (int cd = 0; cd < 4; ++cd) {
            ushort4 o;
            o.x = f2bf(oacc[r][cd][0] * inv); o.y = f2bf(oacc[r][cd][1] * inv);
            o.z = f2bf(oacc[r][cd][2] * inv); o.w = f2bf(oacc[r][cd][3] * inv);
            *(ushort4*)&orow[16 * cd] = o;
        }
    }
}

extern "C" void kernel_launch(void* const* d_in, const int* in_sizes, int n_in,
                              void* d_out, int out_size, void* d_ws, size_t ws_size,
                              hipStream_t stream) {
    const float* x      = (const float*)d_in[0];
    const float* w_qkv  = (const float*)d_in[1];
    const float* b_qkv  = (const float*)d_in[2];
    const float* w_proj = (const float*)d_in[3];
    const float* b_proj = (const float*)d_in[4];
    float* out = (float*)d_out;
    u16* ws = (u16*)d_ws;

    prep<<<3648, 256, 0, stream>>>(x, w_qkv, w_proj, ws);
    gemm_bt<1><<<dim3(18, 64), 256, 0, stream>>>(ws + XOFF, ws + WQOFF, b_qkv, nullptr, ws);
    flash_attn<<<dim3(8, 96), 256, 0, stream>>>(ws, ws + AOFF);
    gemm_bt<0><<<dim3(6, 64), 256, 0, stream>>>(ws + AOFF, ws + WPOFF, b_proj, out, nullptr);
}

// Round 8
// 204.131 us; speedup vs baseline: 1.0680x; 1.0174x over previous
//
#include <hip/hip_runtime.h>
#include <cstdint>

#define DIM 768
#define NH 12
#define HD 64
#define SEQ 1024
#define NBH 96

// ws layout (u16 elements)
#define QOFF  ((size_t)0)
#define KOFF  ((size_t)6291456)
#define VOFF  ((size_t)12582912)
#define AOFF  ((size_t)18874368)   // attn output bf16 [8192][768]
#define XOFF  ((size_t)25165824)   // x bf16
#define WQOFF ((size_t)31457280)   // w_qkv^T bf16 [2304][768]
#define WPOFF ((size_t)33226752)   // w_proj^T bf16 [768][768]

#define QSCALE 0.18033688f  /* 0.125 * log2(e) */

// s_waitcnt immediates: vmcnt[3:0]@[3:0], expcnt@[6:4], lgkmcnt@[11:8], vmcnt[5:4]@[15:14]
#define WAIT_VM0   __builtin_amdgcn_s_waitcnt(0x0F70)  /* vmcnt(0) only  */
#define BAR        __builtin_amdgcn_s_barrier()
#define CFENCE     __asm__ __volatile__("" ::: "memory")

typedef __attribute__((ext_vector_type(8))) __bf16 bf16x8;
typedef __attribute__((ext_vector_type(2))) __bf16 bf16x2;
typedef __attribute__((ext_vector_type(4))) float f32x4;
typedef __attribute__((ext_vector_type(4))) short s16x4;
typedef unsigned short u16;

__device__ __forceinline__ u16 f2bf(float f) {
    union { float f; unsigned u; } x; x.f = f;
    unsigned r = x.u + 0x7fffu + ((x.u >> 16) & 1u);
    return (u16)(r >> 16);
}

__device__ __forceinline__ unsigned pkbf(float a, float b) {
#if __has_builtin(__builtin_amdgcn_cvt_pk_bf16_f32)
    bf16x2 v = __builtin_amdgcn_cvt_pk_bf16_f32(a, b);
    union { bf16x2 v; unsigned u; } c; c.v = v; return c.u;
#else
    return (unsigned)f2bf(a) | ((unsigned)f2bf(b) << 16);
#endif
}

__device__ __forceinline__ void async_cp16(const void* g, void* l) {
    __builtin_amdgcn_global_load_lds((const __attribute__((address_space(1))) void*)g,
                                     (__attribute__((address_space(3))) void*)l, 16, 0, 0);
}

// ---- fused prep: x fp32->bf16 (2 float4/thread), plus both weight transposes
__global__ __launch_bounds__(256) void prep(const float* __restrict__ x,
                                            const float* __restrict__ wq,
                                            const float* __restrict__ wp,
                                            u16* __restrict__ ws) {
    const int bid = blockIdx.x;
    const int tid = threadIdx.x;
    if (bid < 3072) {
        size_t i = (size_t)bid * 512 + tid;
#pragma unroll
        for (int j = 0; j < 2; ++j, i += 256) {
            float4 v = *(const float4*)&x[i * 4];
            ushort4 o;
            o.x = f2bf(v.x); o.y = f2bf(v.y); o.z = f2bf(v.z); o.w = f2bf(v.w);
            *(ushort4*)&ws[XOFF + i * 4] = o;
        }
        return;
    }
    __shared__ float T[64][65];
    const float* w; u16* wt; int N, bx, by;
    if (bid < 3504) { int b = bid - 3072; w = wq; wt = ws + WQOFF; N = 2304; bx = b % 36; by = b / 36; }
    else            { int b = bid - 3504; w = wp; wt = ws + WPOFF; N = 768;  bx = b % 12; by = b / 12; }
    const int K = 768;
    const int k0 = by * 64, n0 = bx * 64;
    const int r = tid >> 4, c4 = (tid & 15) * 4;
#pragma unroll
    for (int i = 0; i < 4; ++i) {
        float4 v = *(const float4*)&w[(size_t)(k0 + r + 16 * i) * N + n0 + c4];
        T[r + 16 * i][c4 + 0] = v.x; T[r + 16 * i][c4 + 1] = v.y;
        T[r + 16 * i][c4 + 2] = v.z; T[r + 16 * i][c4 + 3] = v.w;
    }
    __syncthreads();
#pragma unroll
    for (int i = 0; i < 4; ++i) {
        int rr = r + 16 * i;
        ushort4 o;
        o.x = f2bf(T[c4 + 0][rr]); o.y = f2bf(T[c4 + 1][rr]);
        o.z = f2bf(T[c4 + 2][rr]); o.w = f2bf(T[c4 + 3][rr]);
        *(ushort4*)&wt[(size_t)(n0 + rr) * K + k0 + c4] = o;
    }
}

// ---- GEMM, R3 single-buffer structure, parametric N-tile.
// Tile = 128m x (32*NC)n, BK=64, global_load_lds w=16, XOR-8 swizzle.
// Fragment loads split per-kc (live frags 32 VGPR not 64) + launch_bounds(256,3)
// to fit 3 waves/SIMD (VGPR+AGPR <= 170).
// EPI=0: out fp32 [M][768] + bias.  EPI=1: qkv scatter (Q prescaled, V transposed).
template <int EPI, int NC>
__global__ __launch_bounds__(256, 3) void gemm_bt(const u16* __restrict__ A,
                                                  const u16* __restrict__ Bt,
                                                  const float* __restrict__ bias,
                                                  float* __restrict__ outf,
                                                  u16* __restrict__ outq) {
    __shared__ __align__(16) u16 As[128 * 64];
    __shared__ __align__(16) u16 Bs[32 * NC * 64];
    const int tid = threadIdx.x;
    const int lane = tid & 63;
    const int w = tid >> 6;
    const int wm = w >> 1, wn = w & 1;
    const int m0 = blockIdx.y * 128, n0 = blockIdx.x * (32 * NC);

    const int lgrp = lane >> 3;             // row-within-8
    const int gg = (lane & 7) ^ lgrp;       // swizzled global k-group for staging
    const u16* ga = A  + (size_t)(m0 + w * 32 + lgrp) * 768 + gg * 8;
    const u16* gb = Bt + (size_t)(n0 + w * 8 * NC + lgrp) * 768 + gg * 8;
    u16* lba = As + w * 32 * 64;
    u16* lbb = Bs + w * 8 * NC * 64;

    const int l15 = lane & 15, qg = lane >> 4, q4 = qg * 4;

    int aoff[4][2], boff[NC][2];
#pragma unroll
    for (int r = 0; r < 4; ++r) {
        int row = 64 * wm + 16 * r + l15;
#pragma unroll
        for (int kc = 0; kc < 2; ++kc)
            aoff[r][kc] = row * 64 + (((4 * kc + qg) ^ (row & 7)) << 3);
    }
#pragma unroll
    for (int c = 0; c < NC; ++c) {
        int row = 16 * NC * wn + 16 * c + l15;
#pragma unroll
        for (int kc = 0; kc < 2; ++kc)
            boff[c][kc] = row * 64 + (((4 * kc + qg) ^ (row & 7)) << 3);
    }

    f32x4 acc[4][NC] = {};

    for (int k0 = 0; k0 < 768; k0 += 64) {
#pragma unroll
        for (int i = 0; i < 4; ++i)
            async_cp16(ga + (size_t)i * 8 * 768 + k0, lba + i * 512);
#pragma unroll
        for (int i = 0; i < NC; ++i)
            async_cp16(gb + (size_t)i * 8 * 768 + k0, lbb + i * 512);
        __syncthreads();
#pragma unroll
        for (int kc = 0; kc < 2; ++kc) {
            bf16x8 af[4], bfr[NC];
#pragma unroll
            for (int r = 0; r < 4; ++r) af[r] = *(const bf16x8*)&As[aoff[r][kc]];
#pragma unroll
            for (int c = 0; c < NC; ++c) bfr[c] = *(const bf16x8*)&Bs[boff[c][kc]];
#pragma unroll
            for (int r = 0; r < 4; ++r)
#pragma unroll
                for (int c = 0; c < NC; ++c)
                    acc[r][c] = __builtin_amdgcn_mfma_f32_16x16x32_bf16(af[r], bfr[c], acc[r][c], 0, 0, 0);
        }
        __syncthreads();
    }

#pragma unroll
    for (int r = 0; r < 4; ++r) {
#pragma unroll
        for (int c = 0; c < NC; ++c) {
            const int cg = n0 + 16 * NC * wn + 16 * c + l15;
            const float bv = bias[cg];
            const int mb = m0 + 64 * wm + 16 * r + q4;
            if constexpr (EPI == 0) {
#pragma unroll
                for (int g = 0; g < 4; ++g)
                    outf[(size_t)(mb + g) * DIM + cg] = acc[r][c][g] + bv;
            } else {
                const int which = (cg >= 1536) ? 2 : (cg >= 768 ? 1 : 0);  // uniform over l15
                const int rem = cg - which * 768;
                const int h = rem >> 6, d = rem & 63;
                const int b = mb >> 10, q = mb & 1023;
                if (which == 0) {
#pragma unroll
                    for (int g = 0; g < 4; ++g)
                        outq[QOFF + ((size_t)(b * NH + h) * SEQ + q + g) * HD + d] =
                            f2bf((acc[r][c][g] + bv) * QSCALE);
                } else if (which == 1) {
#pragma unroll
                    for (int g = 0; g < 4; ++g)
                        outq[KOFF + ((size_t)(b * NH + h) * SEQ + q + g) * HD + d] =
                            f2bf(acc[r][c][g] + bv);
                } else {
                    ushort4 pk;
                    pk.x = f2bf(acc[r][c][0] + bv); pk.y = f2bf(acc[r][c][1] + bv);
                    pk.z = f2bf(acc[r][c][2] + bv); pk.w = f2bf(acc[r][c][3] + bv);
                    *(ushort4*)&outq[VOFF + ((size_t)(b * NH + h) * HD + d) * SEQ + q] = pk;
                }
            }
        }
    }
}

// ---- Flash attention v4 (unchanged): P never touches LDS.
// St = K·Q^T via 16x16x32 (A=K LDS, B=Q regs) -> C-layout col=q=l15, row=key=qg*4+reg,
// which IS the 16x16x16 B-operand layout -> PV directly from regs.
// K,V async dbuf staging; ONE barrier per kt-tile.
__global__ __launch_bounds__(256) void flash_attn(const u16* __restrict__ ws, u16* __restrict__ attn_out) {
    __shared__ __align__(16) u16 Ks[2][64 * 64];
    __shared__ __align__(16) u16 Vs[2][64 * 64];

    const int tid = threadIdx.x;
    const int lane = tid & 63;
    const int wv = tid >> 6;
    const int qt = blockIdx.x;   // 0..7
    const int bh = blockIdx.y;   // 0..95
    const u16* qp = ws + QOFF + (size_t)bh * SEQ * HD;
    const u16* kp = ws + KOFF + (size_t)bh * SEQ * HD;
    const u16* vp = ws + VOFF + (size_t)bh * HD * SEQ;

    const int l15 = lane & 15, qg = lane >> 4, q8 = qg * 8;
    const int l7 = l15 & 7;

    bf16x8 bq[2][2];
#pragma unroll
    for (int r = 0; r < 2; ++r)
#pragma unroll
        for (int kc = 0; kc < 2; ++kc)
            bq[r][kc] = *(const bf16x8*)&qp[(size_t)(qt * 128 + 32 * wv + 16 * r + l15) * HD + 32 * kc + q8];

    const int lgrp = lane >> 3;
    const int gg = (lane & 7) ^ lgrp;
    auto stage = [&](int buf, int ktv) {
#pragma unroll
        for (int i = 0; i < 2; ++i) {
            async_cp16(kp + (size_t)(ktv * 64 + wv * 16 + i * 8 + lgrp) * 64 + gg * 8,
                       &Ks[buf][(wv * 16 + i * 8) * 64]);
            async_cp16(vp + (size_t)(wv * 16 + i * 8 + lgrp) * SEQ + ktv * 64 + gg * 8,
                       &Vs[buf][(wv * 16 + i * 8) * 64]);
        }
    };
    stage(0, 0);

    int akoff[4][2], avoff[4][4];
#pragma unroll
    for (int c = 0; c < 4; ++c) {
#pragma unroll
        for (int kc = 0; kc < 2; ++kc)
            akoff[c][kc] = (16 * c + l15) * 64 + (((4 * kc + qg) ^ l7) << 3);
#pragma unroll
        for (int cd = 0; cd < 4; ++cd)
            avoff[c][cd] = (16 * cd + l15) * 64 + (((2 * c + (qg >> 1)) ^ l7) << 3) + (qg & 1) * 4;
    }

    f32x4 oacc[2][4] = {};   // O^T: D col=q=l15, row=d=16cd+qg*4+reg
    float lsum[2] = {0.f, 0.f};

    for (int kt = 0; kt < 16; ++kt) {
        const int cur = kt & 1;
        WAIT_VM0;
        BAR;
        CFENCE;
        if (kt < 15) stage(cur ^ 1, kt + 1);

        f32x4 sacc[4][2] = {};
#pragma unroll
        for (int c = 0; c < 4; ++c) {
#pragma unroll
            for (int kc = 0; kc < 2; ++kc) {
                bf16x8 ak = *(const bf16x8*)&Ks[cur][akoff[c][kc]];
#pragma unroll
                for (int r = 0; r < 2; ++r)
                    sacc[c][r] = __builtin_amdgcn_mfma_f32_16x16x32_bf16(ak, bq[r][kc], sacc[c][r], 0, 0, 0);
            }
        }

        s16x4 pf[4][2];
#pragma unroll
        for (int c = 0; c < 4; ++c) {
#pragma unroll
            for (int r = 0; r < 2; ++r) {
                float p0 = __builtin_amdgcn_exp2f(sacc[c][r][0]);
                float p1 = __builtin_amdgcn_exp2f(sacc[c][r][1]);
                float p2 = __builtin_amdgcn_exp2f(sacc[c][r][2]);
                float p3 = __builtin_amdgcn_exp2f(sacc[c][r][3]);
                lsum[r] += (p0 + p1) + (p2 + p3);
                union { uint2 u; s16x4 v; } pk;
                pk.u.x = pkbf(p0, p1); pk.u.y = pkbf(p2, p3);
                pf[c][r] = pk.v;
            }
        }

#pragma unroll
        for (int c = 0; c < 4; ++c) {
            s16x4 av[4];
#pragma unroll
            for (int cd = 0; cd < 4; ++cd)
                av[cd] = *(const s16x4*)&Vs[cur][avoff[c][cd]];
#pragma unroll
            for (int r = 0; r < 2; ++r)
#pragma unroll
                for (int cd = 0; cd < 4; ++cd)
                    oacc[r][cd] = __builtin_amdgcn_mfma_f32_16x16x16bf16_1k(av[cd], pf[c][r], oacc[r][cd], 0, 0, 0);
        }
    }

#pragma unroll
    for (int r = 0; r < 2; ++r) {
        lsum[r] += __shfl_xor(lsum[r], 16);
        lsum[r] += __shfl_xor(lsum[r], 32);
    }

    const int b = bh / NH, h = bh % NH;
#pragma unroll
    for (int r = 0; r < 2; ++r) {
        const float inv = 1.f / lsum[r];
        const int qrow = qt * 128 + 32 * wv + 16 * r + l15;
        u16* orow = attn_out + (size_t)(b * SEQ + qrow) * DIM + h * HD + qg * 4;
#pragma unroll
        for (int cd = 0; cd < 4; ++cd) {
            ushort4 o;
            o.x = f2bf(oacc[r][cd][0] * inv); o.y = f2bf(oacc[r][cd][1] * inv);
            o.z = f2bf(oacc[r][cd][2] * inv); o.w = f2bf(oacc[r][cd][3] * inv);
            *(ushort4*)&orow[16 * cd] = o;
        }
    }
}

extern "C" void kernel_launch(void* const* d_in, const int* in_sizes, int n_in,
                              void* d_out, int out_size, void* d_ws, size_t ws_size,
                              hipStream_t stream) {
    const float* x      = (const float*)d_in[0];
    const float* w_qkv  = (const float*)d_in[1];
    const float* b_qkv  = (const float*)d_in[2];
    const float* w_proj = (const float*)d_in[3];
    const float* b_proj = (const float*)d_in[4];
    float* out = (float*)d_out;
    u16* ws = (u16*)d_ws;

    prep<<<3648, 256, 0, stream>>>(x, w_qkv, w_proj, ws);
    gemm_bt<1, 4><<<dim3(18, 64), 256, 0, stream>>>(ws + XOFF, ws + WQOFF, b_qkv, nullptr, ws);
    flash_attn<<<dim3(8, 96), 256, 0, stream>>>(ws, ws + AOFF);
    gemm_bt<0, 2><<<dim3(12, 64), 256, 0, stream>>>(ws + AOFF, ws + WPOFF, b_proj, out, nullptr);
}